// Round 13
// baseline (1003.957 us; speedup 1.0000x reference)
//
#include <hip/hip_runtime.h>
#include <cstdint>
#include <cstddef>

#define HW 16384  // 128*128
typedef float v2f __attribute__((ext_vector_type(2)));
typedef __attribute__((ext_vector_type(4))) float f32x4_t;
typedef __attribute__((ext_vector_type(8))) short bf16x8;

__device__ __forceinline__ unsigned short f2bf(float f) {
  unsigned int u = __float_as_uint(f);
  unsigned int r = (u + 0x7FFFu + ((u >> 16) & 1u)) >> 16;  // RNE
  return (unsigned short)r;
}

// ---------------- weight pack ----------------
// Region A (g < 9216): Wpk interleaved [mt(16)][kc(9)][lane(64)][hi8|mid8|lo8]
//   oc = mt*16 + (lane&15); k = kc*32 + (lane>>4)*8 + jj  (dense k = ic*9+tap, k<270)
//   w2 = hi + mid + lo EXACTLY (24-bit mantissa = 3 x 8-bit bf16 chunks).
// Region B: w1p pairs for conv1 (3 oc-groups of 10 -> 5 pairs).
__global__ __launch_bounds__(256) void k_packw(const float* __restrict__ w1,
                                               const float* __restrict__ w2,
                                               v2f* __restrict__ w1p,
                                               unsigned short* __restrict__ Wpk) {
  int g = blockIdx.x * 256 + threadIdx.x;
  if (g < 9216) {
    int mt = g / 576;
    int rem = g - mt * 576;
    int kc = rem >> 6, lane = rem & 63;
    int oc = mt * 16 + (lane & 15);
    unsigned int hbits[4], mbits[4], lbits[4];
#pragma unroll
    for (int p = 0; p < 4; ++p) { hbits[p] = 0; mbits[p] = 0; lbits[p] = 0; }
#pragma unroll
    for (int jj = 0; jj < 8; ++jj) {
      int k = kc * 32 + ((lane >> 4) << 3) + jj;
      float val = (oc < 250 && k < 270) ? w2[(size_t)oc * 270 + k] : 0.f;
      unsigned short h = f2bf(val);
      float r1 = val - __uint_as_float((unsigned int)h << 16);  // exact
      unsigned short m = f2bf(r1);
      float r2 = r1 - __uint_as_float((unsigned int)m << 16);   // exact
      unsigned short l = f2bf(r2);                              // exact: <=8 bits left
      hbits[jj >> 1] |= (unsigned int)h << ((jj & 1) * 16);
      mbits[jj >> 1] |= (unsigned int)m << ((jj & 1) * 16);
      lbits[jj >> 1] |= (unsigned int)l << ((jj & 1) * 16);
    }
    size_t off = (size_t)g * 24;
    *(uint4*)&Wpk[off] = make_uint4(hbits[0], hbits[1], hbits[2], hbits[3]);
    *(uint4*)&Wpk[off + 8] = make_uint4(mbits[0], mbits[1], mbits[2], mbits[3]);
    *(uint4*)&Wpk[off + 16] = make_uint4(lbits[0], lbits[1], lbits[2], lbits[3]);
    return;
  }
  int i = g - 9216;
  if (i < 2250) {
    int m = i % 5, k = (i / 5) % 25, ic = (i / 125) % 6, ocg = i / 750;
    int g0 = ocg * 10 + 2 * m;
    w1p[i] = (v2f){w1[(g0 * 6 + ic) * 25 + k], w1[((g0 + 1) * 6 + ic) * 25 + k]};
  }
}

// ---------------- conv1 + fire(15) + maxpool 2x2 ----------------
// grid (64 tiles, 3 oc-groups, 15 t), block 256 (16x16). Thread = 1 pooled pixel
// (2x2 conv outs) x 5 oc-pairs (10 oc). LDS double-buffered.
__global__ __launch_bounds__(256, 4) void k_conv1(const float* __restrict__ x,
                                                  const v2f* __restrict__ w1p,
                                                  uint8_t* __restrict__ spk_pool) {
  const int tile = blockIdx.x, ocg = blockIdx.y, t = blockIdx.z;
  const int oc0 = ocg * 10;
  const int tid = threadIdx.x;
  const int tx = tid & 15, ty = tid >> 4;
  const int px0 = (tile & 7) << 4, py0 = (tile >> 3) << 4;
  __shared__ float sx[2][36 * 38];
  const int iy0 = (py0 << 1) - 2, ix0 = (px0 << 1) - 2;  // pad=2

  int goff[6], soff[6];
  bool act[6];
#pragma unroll
  for (int j = 0; j < 6; ++j) {
    int idx = tid + 256 * j;
    bool a = idx < 1296;
    int r = idx / 36, c = idx - r * 36;
    int gy = iy0 + r, gx = ix0 + c;
    bool inb = a && (unsigned)gy < 256u && (unsigned)gx < 256u;
    goff[j] = inb ? ((gy << 8) + gx) : -1;
    soff[j] = a ? (r * 38 + c) : 0;
    act[j] = a;
  }

  v2f acc2[5][4];
#pragma unroll
  for (int m = 0; m < 5; ++m)
#pragma unroll
    for (int j = 0; j < 4; ++j) acc2[m][j] = (v2f){0.f, 0.f};

  const float* xt = x + ((size_t)(t * 6) << 16);
  float v[6];
#pragma unroll
  for (int j = 0; j < 6; ++j) v[j] = (goff[j] >= 0) ? xt[goff[j]] : 0.f;
#pragma unroll
  for (int j = 0; j < 6; ++j)
    if (act[j]) sx[0][soff[j]] = v[j];
  __syncthreads();

  for (int ic = 0; ic < 6; ++ic) {
    const int cur = ic & 1, nxt = cur ^ 1;
    if (ic < 5) {
      const float* xp = xt + ((size_t)(ic + 1) << 16);
#pragma unroll
      for (int j = 0; j < 6; ++j) v[j] = (goff[j] >= 0) ? xp[goff[j]] : 0.f;
    }
    float win_[6][6];
#pragma unroll
    for (int r = 0; r < 6; ++r) {
      float2 a = *(const float2*)&sx[cur][(2 * ty + r) * 38 + 2 * tx];
      float2 b = *(const float2*)&sx[cur][(2 * ty + r) * 38 + 2 * tx + 2];
      float2 c = *(const float2*)&sx[cur][(2 * ty + r) * 38 + 2 * tx + 4];
      win_[r][0] = a.x; win_[r][1] = a.y; win_[r][2] = b.x;
      win_[r][3] = b.y; win_[r][4] = c.x; win_[r][5] = c.y;
    }
    const v2f* wp = w1p + ((size_t)(ocg * 6 + ic) * 25) * 5;
#pragma unroll
    for (int k = 0; k < 25; ++k) {
      const int ky = k / 5, kx = k % 5;
      v2f s0 = (v2f){win_[ky][kx], win_[ky][kx]};
      v2f s1 = (v2f){win_[ky][kx + 1], win_[ky][kx + 1]};
      v2f s2 = (v2f){win_[ky + 1][kx], win_[ky + 1][kx]};
      v2f s3 = (v2f){win_[ky + 1][kx + 1], win_[ky + 1][kx + 1]};
#pragma unroll
      for (int m = 0; m < 5; ++m) {
        v2f wv = wp[k * 5 + m];  // block-uniform -> SGPR pair
        acc2[m][0] += wv * s0;
        acc2[m][1] += wv * s1;
        acc2[m][2] += wv * s2;
        acc2[m][3] += wv * s3;
      }
    }
    if (ic < 5) {
#pragma unroll
      for (int j = 0; j < 6; ++j)
        if (act[j]) sx[nxt][soff[j]] = v[j];
    }
    __syncthreads();
  }
#pragma unroll
  for (int g = 0; g < 10; ++g) {
    const int m = g >> 1;
    float a0 = (g & 1) ? acc2[m][0].y : acc2[m][0].x;
    float a1 = (g & 1) ? acc2[m][1].y : acc2[m][1].x;
    float a2 = (g & 1) ? acc2[m][2].y : acc2[m][2].x;
    float a3 = (g & 1) ? acc2[m][3].y : acc2[m][3].x;
    int spike = (a0 > 15.f) || (a1 > 15.f) || (a2 > 15.f) || (a3 > 15.f);
    spk_pool[((size_t)(t * 30 + oc0 + g) << 14) + ((size_t)(py0 + ty) << 7) + (px0 + tx)] =
        (uint8_t)spike;
  }
}

// ---------------- conv2 via MFMA (exact 3-term bf16 split, dense K=288) ----------------
// grid (256 n-tiles, 15 t), block 256 (4 waves). Block = 64 locs x all 250 ocs.
// Coalesced raw-stripe staging -> register im2col expand -> 9 k-chunk MFMA loop.
// Block-level zero-skip; kc loop unroll(3) lets scheduler hoist weight loads.
__global__ __launch_bounds__(256, 3) void k_conv2(const uint8_t* __restrict__ spk_pool,
                                                  const unsigned short* __restrict__ Wpk,
                                                  float* __restrict__ pot2,
                                                  unsigned long long* __restrict__ mp) {
  const int nt = blockIdx.x, t = blockIdx.y;
  const int y = nt >> 1, x0 = (nt & 1) << 6;
  const int tid = threadIdx.x;
  __shared__ unsigned short Bs[64 * 288];        // 36,864 B
  __shared__ unsigned char raw[30 * 3 * 68];     //  6,120 B
  __shared__ unsigned long long mx[64];
  __shared__ int sFlag[4];
  if (tid < 64) mx[tid] = 0ULL;

  // ---- stage raw stripe (coalesced byte loads) + zero detection ----
  unsigned int nz = 0;
  for (int idx = tid; idx < 30 * 204; idx += 256) {
    int ic = idx / 204;
    int rem = idx - ic * 204;
    int row = rem / 68, col = rem - row * 68;
    int gy = y - 1 + row, gx = x0 - 1 + col;
    unsigned char v = 0;
    if ((unsigned)gy < 128u && (unsigned)gx < 128u && col < 67)
      v = spk_pool[((size_t)(t * 30 + ic) << 14) + (gy << 7) + gx];
    raw[idx] = v;
    nz |= v;
  }
  {
    bool wnz = __any(nz != 0);
    if ((tid & 63) == 0) sFlag[tid >> 6] = wnz ? 1 : 0;
  }
  __syncthreads();
  const int flag = sFlag[0] | sFlag[1] | sFlag[2] | sFlag[3];

  const int w = tid >> 6, lane = tid & 63;
  const int bcol = lane & 15, bq = lane >> 4;
  f32x4_t acc[4][4];
#pragma unroll
  for (int i = 0; i < 4; ++i)
#pragma unroll
    for (int j = 0; j < 4; ++j) acc[i][j] = (f32x4_t){0.f, 0.f, 0.f, 0.f};

  if (flag) {
    // ---- expand to B panel: thread = (n = tid&63, q = tid>>6 covers k in [72q,72q+72)) ----
    const int n = tid & 63, q = tid >> 6;
#pragma unroll
    for (int c = 0; c < 9; ++c) {
      unsigned int bits[4] = {0u, 0u, 0u, 0u};
#pragma unroll
      for (int e = 0; e < 8; ++e) {
        const int m = c * 8 + e;        // 0..71, compile-time
        const int mc = m / 9, tap = m - mc * 9;
        const int dy = tap / 3, dx = tap - dy * 3;
        const int ic = q * 8 + mc;      // q runtime
        unsigned int v = 0u;
        if (ic < 30)
          v = raw[ic * 204 + dy * 68 + n + dx] ? 0x3F80u : 0u;
        bits[e >> 1] |= v << ((e & 1) * 16);
      }
      *(uint4*)&Bs[n * 288 + q * 72 + c * 8] = make_uint4(bits[0], bits[1], bits[2], bits[3]);
    }
    __syncthreads();

    // ---- MFMA main loop: 9 k-chunks of 32 ----
#pragma unroll 3
    for (int kc = 0; kc < 9; ++kc) {
      bf16x8 bb[4];
#pragma unroll
      for (int j = 0; j < 4; ++j)
        bb[j] = *(const bf16x8*)&Bs[(j * 16 + bcol) * 288 + kc * 32 + bq * 8];
      bf16x8 ah[4], am[4], al[4];
#pragma unroll
      for (int i = 0; i < 4; ++i) {
        const size_t off = (size_t)(((w * 4 + i) * 9 + kc) * 64 + lane) * 24;
        ah[i] = *(const bf16x8*)&Wpk[off];
        am[i] = *(const bf16x8*)&Wpk[off + 8];
        al[i] = *(const bf16x8*)&Wpk[off + 16];
      }
#pragma unroll
      for (int i = 0; i < 4; ++i)
#pragma unroll
        for (int j = 0; j < 4; ++j) {
          acc[i][j] = __builtin_amdgcn_mfma_f32_16x16x32_bf16(ah[i], bb[j], acc[i][j], 0, 0, 0);
          acc[i][j] = __builtin_amdgcn_mfma_f32_16x16x32_bf16(am[i], bb[j], acc[i][j], 0, 0, 0);
          acc[i][j] = __builtin_amdgcn_mfma_f32_16x16x32_bf16(al[i], bb[j], acc[i][j], 0, 0, 0);
        }
    }
    __syncthreads();
  }

  // ---- epilogue: fire(10) + pot2 store + per-loc packed max ----
  // C/D layout: col(n) = lane&15, row(m) = (lane>>4)*4 + reg
#pragma unroll
  for (int j = 0; j < 4; ++j) {
    const int loc = (y << 7) + x0 + j * 16 + bcol;
    unsigned long long best = 0ULL;
#pragma unroll
    for (int i = 0; i < 4; ++i) {
      const int mt = w * 4 + i;
#pragma unroll
      for (int r = 0; r < 4; ++r) {
        const int oc = mt * 16 + (bq << 2) + r;
        float v = acc[i][j][r];
        v = v > 10.f ? v : 0.f;
        if (oc < 250) {
          pot2[((size_t)(t * 250 + oc) << 14) + loc] = v;
          unsigned long long pk =
              ((unsigned long long)__float_as_uint(v) << 32) |
              (unsigned long long)(1023 - oc);
          best = pk > best ? pk : best;
        }
      }
    }
    atomicMax(&mx[j * 16 + bcol], best);
  }
  __syncthreads();
  if (tid < 64) mp[(size_t)t * HW + (y << 7) + x0 + tid] = mx[tid];
}

// ---------------- inhibition combine per location (round-9 exact) ----------------
__global__ __launch_bounds__(64) void k_inhib(const float* __restrict__ pot2,
                                              const unsigned long long* __restrict__ mp,
                                              int* __restrict__ win,
                                              float* __restrict__ nspv,
                                              float* __restrict__ valv,
                                              float* __restrict__ sv) {
  const int loc = (blockIdx.x << 6) + threadIdx.x;
  int cnt = 0;
  float last = 0.f;
  unsigned long long pks[15];
#pragma unroll
  for (int t = 0; t < 15; ++t) {
    pks[t] = mp[t * HW + loc];
    float v = __uint_as_float((unsigned)(pks[t] >> 32));
    cnt += (v > 0.f) ? 1 : 0;
    if (t == 14) last = v;
  }
  const int spiked = (last > 0.f) ? 1 : 0;
  int ft = 15 - cnt;
  if (ft > 14) ft = 14;
  if (ft < 0) ft = 0;
  int wc = 1023 - (int)(pks[ft] & 1023ULL);
  if ((unsigned)wc > 249u) wc = 0;
  int nsp = 0;
#pragma unroll
  for (int t = 0; t < 15; ++t) {
    float v = pot2[((size_t)(t * 250 + wc) << 14) + loc];
    v = spiked ? v : 0.f;
    sv[t * HW + loc] = v;
    nsp += (v > 0.f) ? 1 : 0;
  }
  int ft2 = 15 - nsp;
  if (ft2 > 14) ft2 = 14;
  float value = spiked ? pot2[((size_t)(ft2 * 250 + wc) << 14) + loc] : 0.f;
  win[loc] = spiked ? wc : -1;
  nspv[loc] = (float)nsp;
  valv[loc] = value;
}

// ---------------- finalize: loc-major float4 ----------------
// grid (16, 15), block 256. Thread = 4 consecutive locs, loops 250 channels.
__global__ __launch_bounds__(256) void k_final(const int* __restrict__ win,
                                               const float* __restrict__ sv,
                                               float* __restrict__ spk_out,
                                               float* __restrict__ pot_out) {
  const int t = blockIdx.y;
  const int l0 = (blockIdx.x << 10) + (threadIdx.x << 2);
  int4 w4 = *(const int4*)&win[l0];
  float4 v4 = *(const float4*)&sv[t * HW + l0];
  float4 s4;
  s4.x = (v4.x > 0.f) ? 1.f : 0.f;
  s4.y = (v4.y > 0.f) ? 1.f : 0.f;
  s4.z = (v4.z > 0.f) ? 1.f : 0.f;
  s4.w = (v4.w > 0.f) ? 1.f : 0.f;
  float* pp = pot_out + ((size_t)(t * 250) << 14) + l0;
  float* sp = spk_out + ((size_t)(t * 250) << 14) + l0;
  for (int c = 0; c < 250; ++c) {
    float4 pv, sw;
    pv.x = (w4.x == c) ? v4.x : 0.f; sw.x = (w4.x == c) ? s4.x : 0.f;
    pv.y = (w4.y == c) ? v4.y : 0.f; sw.y = (w4.y == c) ? s4.y : 0.f;
    pv.z = (w4.z == c) ? v4.z : 0.f; sw.z = (w4.z == c) ? s4.z : 0.f;
    pv.w = (w4.w == c) ? v4.w : 0.f; sw.w = (w4.w == c) ? s4.w : 0.f;
    *(float4*)&pp[(size_t)c << 14] = pv;
    *(float4*)&sp[(size_t)c << 14] = sw;
  }
}

// ---------------- k-winner selection (single block, round-9 exact) ----------------
__global__ __launch_bounds__(256) void k_select(const int* __restrict__ win,
                                                const float* __restrict__ nspv,
                                                const float* __restrict__ valv,
                                                float* __restrict__ winners) {
  __shared__ float tot[HW];
  __shared__ int wchan[HW];
  __shared__ float redV[256];
  __shared__ int redK[256];
  __shared__ float bcValid[1];
  __shared__ int bcKey[1];
  const int tid = threadIdx.x;

  float lmax = 0.f;
  for (int i = tid; i < HW; i += 256) {
    wchan[i] = win[i];
    lmax = fmaxf(lmax, valv[i]);
  }
  redV[tid] = lmax;
  __syncthreads();
  for (int s = 128; s > 0; s >>= 1) {
    if (tid < s) redV[tid] = fmaxf(redV[tid], redV[tid + s]);
    __syncthreads();
  }
  const float v15 = redV[0] * 15.f;
  __syncthreads();
  for (int i = tid; i < HW; i += 256) tot[i] = nspv[i] * (valv[i] + v15);
  __syncthreads();

  for (int k = 0; k < 8; ++k) {
    float bv = -1.f;
    int bkey = 0x7fffffff;
    for (int i = tid; i < HW; i += 256) {
      float v = tot[i];
      int key = (wchan[i] << 14) + i;
      if (v > bv || (v == bv && key < bkey)) { bv = v; bkey = key; }
    }
    redV[tid] = bv;
    redK[tid] = bkey;
    __syncthreads();
    for (int s = 128; s > 0; s >>= 1) {
      if (tid < s) {
        float ov = redV[tid + s];
        int ok = redK[tid + s];
        if (ov > redV[tid] || (ov == redV[tid] && ok < redK[tid])) {
          redV[tid] = ov;
          redK[tid] = ok;
        }
      }
      __syncthreads();
    }
    if (tid == 0) {
      float mv = redV[0];
      int mk = redK[0];
      int valid = (mv != 0.f) ? 1 : 0;
      int c = mk >> 14, l = mk & (HW - 1);
      winners[k * 3 + 0] = valid ? (float)c : -1.f;
      winners[k * 3 + 1] = valid ? (float)(l >> 7) : -1.f;
      winners[k * 3 + 2] = valid ? (float)(l & 127) : -1.f;
      bcValid[0] = valid ? 1.f : 0.f;
      bcKey[0] = mk;
    }
    __syncthreads();
    if (bcValid[0] > 0.f) {
      int mk = bcKey[0];
      int c = mk >> 14, h = (mk & (HW - 1)) >> 7, w = mk & 127;
      for (int i = tid; i < HW; i += 256) {
        int hh = i >> 7, ww = i & 127;
        int dh = hh - h; if (dh < 0) dh = -dh;
        int dw = ww - w; if (dw < 0) dw = -dw;
        bool m = (wchan[i] == c) || (dh <= 1 && dw <= 1);
        if (m) tot[i] = 0.f;
      }
    }
    __syncthreads();
  }
}

extern "C" void kernel_launch(void* const* d_in, const int* in_sizes, int n_in,
                              void* d_out, int out_size, void* d_ws, size_t ws_size,
                              hipStream_t stream) {
  const float* x = (const float*)d_in[0];
  const float* w1 = (const float*)d_in[1];
  const float* w2 = (const float*)d_in[2];
  (void)in_sizes; (void)n_in; (void)out_size; (void)ws_size;

  float* spk_out = (float*)d_out;
  float* pot_out = spk_out + 61440000;  // pot2 scratch == final pot at winner ch
  float* winners = spk_out + 122880000;

  uint8_t* ws = (uint8_t*)d_ws;
  unsigned long long* mp = (unsigned long long*)ws;   // 1,966,080 B u64 [15][HW]
  uint8_t* spk_pool = ws + 1966080;                   // 7,372,800 B u8
  int* win = (int*)(ws + 9338880);                    //  65,536 B
  float* nspv = (float*)(ws + 9404416);               //  65,536 B
  float* valv = (float*)(ws + 9469952);               //  65,536 B
  float* sv = (float*)(ws + 9535488);                 // 983,040 B [15][HW]
  // Wpk overlaps sv: dead until k_inhib writes sv (conv2 finished reading)
  unsigned short* Wpk = (unsigned short*)(ws + 9535488);  // 442,368 B
  v2f* w1p = (v2f*)(ws + 10518528);                   //  18,000 B

  hipLaunchKernelGGL(k_packw, dim3(45), dim3(256), 0, stream, w1, w2, w1p, Wpk);
  hipLaunchKernelGGL(k_conv1, dim3(64, 3, 15), dim3(256), 0, stream, x, w1p, spk_pool);
  hipLaunchKernelGGL(k_conv2, dim3(256, 15), dim3(256), 0, stream, spk_pool, Wpk, pot_out, mp);
  hipLaunchKernelGGL(k_inhib, dim3(256), dim3(64), 0, stream, pot_out, mp, win, nspv, valv, sv);
  hipLaunchKernelGGL(k_final, dim3(16, 15), dim3(256), 0, stream, win, sv, spk_out, pot_out);
  hipLaunchKernelGGL(k_select, dim3(1), dim3(256), 0, stream, win, nspv, valv, winners);
}

// Round 14
// 982.912 us; speedup vs baseline: 1.0214x; 1.0214x over previous
//
#include <hip/hip_runtime.h>
#include <cstdint>
#include <cstddef>

#define HW 16384  // 128*128
typedef float v2f __attribute__((ext_vector_type(2)));
typedef __attribute__((ext_vector_type(4))) float f32x4_t;
typedef __attribute__((ext_vector_type(8))) short bf16x8;

__device__ __forceinline__ unsigned short f2bf(float f) {
  unsigned int u = __float_as_uint(f);
  unsigned int r = (u + 0x7FFFu + ((u >> 16) & 1u)) >> 16;  // RNE
  return (unsigned short)r;
}

// ---------------- weight pack (round-12 exact) ----------------
// Region A (g < 9216): Wpk interleaved [mt(16)][kc(9)][lane(64)][hi8|mid8|lo8]
//   oc = mt*16 + (lane&15); k = kc*32 + (lane>>4)*8 + jj  (dense k = ic*9+tap, k<270)
//   w2 = hi + mid + lo EXACTLY (24-bit mantissa = 3 x 8-bit bf16 chunks).
// Region B: w1p pairs for conv1 (5 oc-groups of 6 -> 3 pairs).
__global__ __launch_bounds__(256) void k_packw(const float* __restrict__ w1,
                                               const float* __restrict__ w2,
                                               v2f* __restrict__ w1p,
                                               unsigned short* __restrict__ Wpk) {
  int g = blockIdx.x * 256 + threadIdx.x;
  if (g < 9216) {
    int mt = g / 576;
    int rem = g - mt * 576;
    int kc = rem >> 6, lane = rem & 63;
    int oc = mt * 16 + (lane & 15);
    unsigned int hbits[4], mbits[4], lbits[4];
#pragma unroll
    for (int p = 0; p < 4; ++p) { hbits[p] = 0; mbits[p] = 0; lbits[p] = 0; }
#pragma unroll
    for (int jj = 0; jj < 8; ++jj) {
      int k = kc * 32 + ((lane >> 4) << 3) + jj;
      float val = (oc < 250 && k < 270) ? w2[(size_t)oc * 270 + k] : 0.f;
      unsigned short h = f2bf(val);
      float r1 = val - __uint_as_float((unsigned int)h << 16);  // exact
      unsigned short m = f2bf(r1);
      float r2 = r1 - __uint_as_float((unsigned int)m << 16);   // exact
      unsigned short l = f2bf(r2);                              // exact: <=8 bits left
      hbits[jj >> 1] |= (unsigned int)h << ((jj & 1) * 16);
      mbits[jj >> 1] |= (unsigned int)m << ((jj & 1) * 16);
      lbits[jj >> 1] |= (unsigned int)l << ((jj & 1) * 16);
    }
    size_t off = (size_t)g * 24;
    *(uint4*)&Wpk[off] = make_uint4(hbits[0], hbits[1], hbits[2], hbits[3]);
    *(uint4*)&Wpk[off + 8] = make_uint4(mbits[0], mbits[1], mbits[2], mbits[3]);
    *(uint4*)&Wpk[off + 16] = make_uint4(lbits[0], lbits[1], lbits[2], lbits[3]);
    return;
  }
  int i = g - 9216;
  if (i < 2250) {
    int m = i % 3, k = (i / 3) % 25, ic = (i / 75) % 6, ocg = i / 450;
    int g0 = ocg * 6 + 2 * m;
    w1p[i] = (v2f){w1[(g0 * 6 + ic) * 25 + k], w1[((g0 + 1) * 6 + ic) * 25 + k]};
  }
}

// ---------------- conv1 + fire(15) + maxpool 2x2 (round-12 exact) ----------------
__global__ __launch_bounds__(256, 4) void k_conv1(const float* __restrict__ x,
                                                  const v2f* __restrict__ w1p,
                                                  uint8_t* __restrict__ spk_pool) {
  const int tile = blockIdx.x, ocg = blockIdx.y, t = blockIdx.z;
  const int oc0 = ocg * 6;
  const int tid = threadIdx.x;
  const int tx = tid & 15, ty = tid >> 4;
  const int px0 = (tile & 7) << 4, py0 = (tile >> 3) << 4;
  __shared__ float sx[2][36 * 38];
  const int iy0 = (py0 << 1) - 2, ix0 = (px0 << 1) - 2;  // pad=2

  int goff[6], soff[6];
  bool act[6];
#pragma unroll
  for (int j = 0; j < 6; ++j) {
    int idx = tid + 256 * j;
    bool a = idx < 1296;
    int r = idx / 36, c = idx - r * 36;
    int gy = iy0 + r, gx = ix0 + c;
    bool inb = a && (unsigned)gy < 256u && (unsigned)gx < 256u;
    goff[j] = inb ? ((gy << 8) + gx) : -1;
    soff[j] = a ? (r * 38 + c) : 0;
    act[j] = a;
  }

  v2f acc2[3][4];
#pragma unroll
  for (int m = 0; m < 3; ++m)
#pragma unroll
    for (int j = 0; j < 4; ++j) acc2[m][j] = (v2f){0.f, 0.f};

  const float* xt = x + ((size_t)(t * 6) << 16);
  float v[6];
#pragma unroll
  for (int j = 0; j < 6; ++j) v[j] = (goff[j] >= 0) ? xt[goff[j]] : 0.f;
#pragma unroll
  for (int j = 0; j < 6; ++j)
    if (act[j]) sx[0][soff[j]] = v[j];
  __syncthreads();

  for (int ic = 0; ic < 6; ++ic) {
    const int cur = ic & 1, nxt = cur ^ 1;
    if (ic < 5) {
      const float* xp = xt + ((size_t)(ic + 1) << 16);
#pragma unroll
      for (int j = 0; j < 6; ++j) v[j] = (goff[j] >= 0) ? xp[goff[j]] : 0.f;
    }
    float win_[6][6];
#pragma unroll
    for (int r = 0; r < 6; ++r) {
      float2 a = *(const float2*)&sx[cur][(2 * ty + r) * 38 + 2 * tx];
      float2 b = *(const float2*)&sx[cur][(2 * ty + r) * 38 + 2 * tx + 2];
      float2 c = *(const float2*)&sx[cur][(2 * ty + r) * 38 + 2 * tx + 4];
      win_[r][0] = a.x; win_[r][1] = a.y; win_[r][2] = b.x;
      win_[r][3] = b.y; win_[r][4] = c.x; win_[r][5] = c.y;
    }
    const v2f* wp = w1p + ((size_t)(ocg * 6 + ic) * 25) * 3;
#pragma unroll
    for (int k = 0; k < 25; ++k) {
      const int ky = k / 5, kx = k % 5;
      v2f s0 = (v2f){win_[ky][kx], win_[ky][kx]};
      v2f s1 = (v2f){win_[ky][kx + 1], win_[ky][kx + 1]};
      v2f s2 = (v2f){win_[ky + 1][kx], win_[ky + 1][kx]};
      v2f s3 = (v2f){win_[ky + 1][kx + 1], win_[ky + 1][kx + 1]};
#pragma unroll
      for (int m = 0; m < 3; ++m) {
        v2f wv = wp[k * 3 + m];  // block-uniform -> SGPR pair
        acc2[m][0] += wv * s0;
        acc2[m][1] += wv * s1;
        acc2[m][2] += wv * s2;
        acc2[m][3] += wv * s3;
      }
    }
    if (ic < 5) {
#pragma unroll
      for (int j = 0; j < 6; ++j)
        if (act[j]) sx[nxt][soff[j]] = v[j];
    }
    __syncthreads();
  }
#pragma unroll
  for (int g = 0; g < 6; ++g) {
    const int m = g >> 1;
    float a0 = (g & 1) ? acc2[m][0].y : acc2[m][0].x;
    float a1 = (g & 1) ? acc2[m][1].y : acc2[m][1].x;
    float a2 = (g & 1) ? acc2[m][2].y : acc2[m][2].x;
    float a3 = (g & 1) ? acc2[m][3].y : acc2[m][3].x;
    int spike = (a0 > 15.f) || (a1 > 15.f) || (a2 > 15.f) || (a3 > 15.f);
    spk_pool[((size_t)(t * 30 + oc0 + g) << 14) + ((size_t)(py0 + ty) << 7) + (px0 + tx)] =
        (uint8_t)spike;
  }
}

// ---------------- conv2 via MFMA (round-12 exact: dense K=288, no skip/unroll) ---------
__global__ __launch_bounds__(256, 3) void k_conv2(const uint8_t* __restrict__ spk_pool,
                                                  const unsigned short* __restrict__ Wpk,
                                                  float* __restrict__ pot2,
                                                  unsigned long long* __restrict__ mp) {
  const int nt = blockIdx.x, t = blockIdx.y;
  const int y = nt >> 1, x0 = (nt & 1) << 6;
  const int tid = threadIdx.x;
  __shared__ unsigned short Bs[64 * 288];        // 36,864 B
  __shared__ unsigned char raw[30 * 3 * 68];     //  6,120 B
  __shared__ unsigned long long mx[64];
  if (tid < 64) mx[tid] = 0ULL;

  // ---- stage raw stripe (coalesced byte loads) ----
  for (int idx = tid; idx < 30 * 204; idx += 256) {
    int ic = idx / 204;
    int rem = idx - ic * 204;
    int row = rem / 68, col = rem - row * 68;
    int gy = y - 1 + row, gx = x0 - 1 + col;
    unsigned char v = 0;
    if ((unsigned)gy < 128u && (unsigned)gx < 128u && col < 67)
      v = spk_pool[((size_t)(t * 30 + ic) << 14) + (gy << 7) + gx];
    raw[idx] = v;
  }
  __syncthreads();

  // ---- expand to B panel: thread = (n = tid&63, q = tid>>6 covers k in [72q,72q+72)) ----
  {
    const int n = tid & 63, q = tid >> 6;
#pragma unroll
    for (int c = 0; c < 9; ++c) {
      unsigned int bits[4] = {0u, 0u, 0u, 0u};
#pragma unroll
      for (int e = 0; e < 8; ++e) {
        const int m = c * 8 + e;        // 0..71, compile-time
        const int mc = m / 9, tap = m - mc * 9;
        const int dy = tap / 3, dx = tap - dy * 3;
        const int ic = q * 8 + mc;      // q runtime
        unsigned int v = 0u;
        if (ic < 30)
          v = raw[ic * 204 + dy * 68 + n + dx] ? 0x3F80u : 0u;
        bits[e >> 1] |= v << ((e & 1) * 16);
      }
      *(uint4*)&Bs[n * 288 + q * 72 + c * 8] = make_uint4(bits[0], bits[1], bits[2], bits[3]);
    }
  }
  __syncthreads();

  // ---- MFMA main loop: 9 k-chunks of 32 ----
  const int w = tid >> 6, lane = tid & 63;
  const int bcol = lane & 15, bq = lane >> 4;
  f32x4_t acc[4][4];
#pragma unroll
  for (int i = 0; i < 4; ++i)
#pragma unroll
    for (int j = 0; j < 4; ++j) acc[i][j] = (f32x4_t){0.f, 0.f, 0.f, 0.f};

  for (int kc = 0; kc < 9; ++kc) {
    bf16x8 bb[4];
#pragma unroll
    for (int j = 0; j < 4; ++j)
      bb[j] = *(const bf16x8*)&Bs[(j * 16 + bcol) * 288 + kc * 32 + bq * 8];
    bf16x8 ah[4], am[4], al[4];
#pragma unroll
    for (int i = 0; i < 4; ++i) {
      const size_t off = (size_t)(((w * 4 + i) * 9 + kc) * 64 + lane) * 24;
      ah[i] = *(const bf16x8*)&Wpk[off];
      am[i] = *(const bf16x8*)&Wpk[off + 8];
      al[i] = *(const bf16x8*)&Wpk[off + 16];
    }
#pragma unroll
    for (int i = 0; i < 4; ++i)
#pragma unroll
      for (int j = 0; j < 4; ++j) {
        acc[i][j] = __builtin_amdgcn_mfma_f32_16x16x32_bf16(ah[i], bb[j], acc[i][j], 0, 0, 0);
        acc[i][j] = __builtin_amdgcn_mfma_f32_16x16x32_bf16(am[i], bb[j], acc[i][j], 0, 0, 0);
        acc[i][j] = __builtin_amdgcn_mfma_f32_16x16x32_bf16(al[i], bb[j], acc[i][j], 0, 0, 0);
      }
  }

  // ---- epilogue: fire(10) + pot2 store + per-loc packed max ----
  // C/D layout: col(n) = lane&15, row(m) = (lane>>4)*4 + reg
#pragma unroll
  for (int j = 0; j < 4; ++j) {
    const int loc = (y << 7) + x0 + j * 16 + bcol;
    unsigned long long best = 0ULL;
#pragma unroll
    for (int i = 0; i < 4; ++i) {
      const int mt = w * 4 + i;
#pragma unroll
      for (int r = 0; r < 4; ++r) {
        const int oc = mt * 16 + (bq << 2) + r;
        float v = acc[i][j][r];
        v = v > 10.f ? v : 0.f;
        if (oc < 250) {
          pot2[((size_t)(t * 250 + oc) << 14) + loc] = v;
          unsigned long long pk =
              ((unsigned long long)__float_as_uint(v) << 32) |
              (unsigned long long)(1023 - oc);
          best = pk > best ? pk : best;
        }
      }
    }
    atomicMax(&mx[j * 16 + bcol], best);
  }
  __syncthreads();
  if (tid < 64) mp[(size_t)t * HW + (y << 7) + x0 + tid] = mx[tid];
}

// ---------------- inhibition combine per location (round-9 exact) ----------------
__global__ __launch_bounds__(64) void k_inhib(const float* __restrict__ pot2,
                                              const unsigned long long* __restrict__ mp,
                                              int* __restrict__ win,
                                              float* __restrict__ nspv,
                                              float* __restrict__ valv,
                                              float* __restrict__ sv) {
  const int loc = (blockIdx.x << 6) + threadIdx.x;
  int cnt = 0;
  float last = 0.f;
  unsigned long long pks[15];
#pragma unroll
  for (int t = 0; t < 15; ++t) {
    pks[t] = mp[t * HW + loc];
    float v = __uint_as_float((unsigned)(pks[t] >> 32));
    cnt += (v > 0.f) ? 1 : 0;
    if (t == 14) last = v;
  }
  const int spiked = (last > 0.f) ? 1 : 0;
  int ft = 15 - cnt;
  if (ft > 14) ft = 14;
  if (ft < 0) ft = 0;
  int wc = 1023 - (int)(pks[ft] & 1023ULL);
  if ((unsigned)wc > 249u) wc = 0;
  int nsp = 0;
#pragma unroll
  for (int t = 0; t < 15; ++t) {
    float v = pot2[((size_t)(t * 250 + wc) << 14) + loc];
    v = spiked ? v : 0.f;
    sv[t * HW + loc] = v;
    nsp += (v > 0.f) ? 1 : 0;
  }
  int ft2 = 15 - nsp;
  if (ft2 > 14) ft2 = 14;
  float value = spiked ? pot2[((size_t)(ft2 * 250 + wc) << 14) + loc] : 0.f;
  win[loc] = spiked ? wc : -1;
  nspv[loc] = (float)nsp;
  valv[loc] = value;
}

// ---------------- finalize: loc-major float4 (round-13 version, kept) ----------------
// grid (16, 15), block 256. Thread = 4 consecutive locs, loops 250 channels.
__global__ __launch_bounds__(256) void k_final(const int* __restrict__ win,
                                               const float* __restrict__ sv,
                                               float* __restrict__ spk_out,
                                               float* __restrict__ pot_out) {
  const int t = blockIdx.y;
  const int l0 = (blockIdx.x << 10) + (threadIdx.x << 2);
  int4 w4 = *(const int4*)&win[l0];
  float4 v4 = *(const float4*)&sv[t * HW + l0];
  float4 s4;
  s4.x = (v4.x > 0.f) ? 1.f : 0.f;
  s4.y = (v4.y > 0.f) ? 1.f : 0.f;
  s4.z = (v4.z > 0.f) ? 1.f : 0.f;
  s4.w = (v4.w > 0.f) ? 1.f : 0.f;
  float* pp = pot_out + ((size_t)(t * 250) << 14) + l0;
  float* sp = spk_out + ((size_t)(t * 250) << 14) + l0;
  for (int c = 0; c < 250; ++c) {
    float4 pv, sw;
    pv.x = (w4.x == c) ? v4.x : 0.f; sw.x = (w4.x == c) ? s4.x : 0.f;
    pv.y = (w4.y == c) ? v4.y : 0.f; sw.y = (w4.y == c) ? s4.y : 0.f;
    pv.z = (w4.z == c) ? v4.z : 0.f; sw.z = (w4.z == c) ? s4.z : 0.f;
    pv.w = (w4.w == c) ? v4.w : 0.f; sw.w = (w4.w == c) ? s4.w : 0.f;
    *(float4*)&pp[(size_t)c << 14] = pv;
    *(float4*)&sp[(size_t)c << 14] = sw;
  }
}

// ---------------- k-winner selection (single block, round-9 exact) ----------------
__global__ __launch_bounds__(256) void k_select(const int* __restrict__ win,
                                                const float* __restrict__ nspv,
                                                const float* __restrict__ valv,
                                                float* __restrict__ winners) {
  __shared__ float tot[HW];
  __shared__ int wchan[HW];
  __shared__ float redV[256];
  __shared__ int redK[256];
  __shared__ float bcValid[1];
  __shared__ int bcKey[1];
  const int tid = threadIdx.x;

  float lmax = 0.f;
  for (int i = tid; i < HW; i += 256) {
    wchan[i] = win[i];
    lmax = fmaxf(lmax, valv[i]);
  }
  redV[tid] = lmax;
  __syncthreads();
  for (int s = 128; s > 0; s >>= 1) {
    if (tid < s) redV[tid] = fmaxf(redV[tid], redV[tid + s]);
    __syncthreads();
  }
  const float v15 = redV[0] * 15.f;
  __syncthreads();
  for (int i = tid; i < HW; i += 256) tot[i] = nspv[i] * (valv[i] + v15);
  __syncthreads();

  for (int k = 0; k < 8; ++k) {
    float bv = -1.f;
    int bkey = 0x7fffffff;
    for (int i = tid; i < HW; i += 256) {
      float v = tot[i];
      int key = (wchan[i] << 14) + i;
      if (v > bv || (v == bv && key < bkey)) { bv = v; bkey = key; }
    }
    redV[tid] = bv;
    redK[tid] = bkey;
    __syncthreads();
    for (int s = 128; s > 0; s >>= 1) {
      if (tid < s) {
        float ov = redV[tid + s];
        int ok = redK[tid + s];
        if (ov > redV[tid] || (ov == redV[tid] && ok < redK[tid])) {
          redV[tid] = ov;
          redK[tid] = ok;
        }
      }
      __syncthreads();
    }
    if (tid == 0) {
      float mv = redV[0];
      int mk = redK[0];
      int valid = (mv != 0.f) ? 1 : 0;
      int c = mk >> 14, l = mk & (HW - 1);
      winners[k * 3 + 0] = valid ? (float)c : -1.f;
      winners[k * 3 + 1] = valid ? (float)(l >> 7) : -1.f;
      winners[k * 3 + 2] = valid ? (float)(l & 127) : -1.f;
      bcValid[0] = valid ? 1.f : 0.f;
      bcKey[0] = mk;
    }
    __syncthreads();
    if (bcValid[0] > 0.f) {
      int mk = bcKey[0];
      int c = mk >> 14, h = (mk & (HW - 1)) >> 7, w = mk & 127;
      for (int i = tid; i < HW; i += 256) {
        int hh = i >> 7, ww = i & 127;
        int dh = hh - h; if (dh < 0) dh = -dh;
        int dw = ww - w; if (dw < 0) dw = -dw;
        bool m = (wchan[i] == c) || (dh <= 1 && dw <= 1);
        if (m) tot[i] = 0.f;
      }
    }
    __syncthreads();
  }
}

extern "C" void kernel_launch(void* const* d_in, const int* in_sizes, int n_in,
                              void* d_out, int out_size, void* d_ws, size_t ws_size,
                              hipStream_t stream) {
  const float* x = (const float*)d_in[0];
  const float* w1 = (const float*)d_in[1];
  const float* w2 = (const float*)d_in[2];
  (void)in_sizes; (void)n_in; (void)out_size; (void)ws_size;

  float* spk_out = (float*)d_out;
  float* pot_out = spk_out + 61440000;  // pot2 scratch == final pot at winner ch
  float* winners = spk_out + 122880000;

  uint8_t* ws = (uint8_t*)d_ws;
  unsigned long long* mp = (unsigned long long*)ws;   // 1,966,080 B u64 [15][HW]
  uint8_t* spk_pool = ws + 1966080;                   // 7,372,800 B u8
  int* win = (int*)(ws + 9338880);                    //  65,536 B
  float* nspv = (float*)(ws + 9404416);               //  65,536 B
  float* valv = (float*)(ws + 9469952);               //  65,536 B
  float* sv = (float*)(ws + 9535488);                 // 983,040 B [15][HW]
  // Wpk overlaps sv: dead until k_inhib writes sv (conv2 finished reading)
  unsigned short* Wpk = (unsigned short*)(ws + 9535488);  // 442,368 B
  v2f* w1p = (v2f*)(ws + 10518528);                   //  18,000 B

  hipLaunchKernelGGL(k_packw, dim3(45), dim3(256), 0, stream, w1, w2, w1p, Wpk);
  hipLaunchKernelGGL(k_conv1, dim3(64, 5, 15), dim3(256), 0, stream, x, w1p, spk_pool);
  hipLaunchKernelGGL(k_conv2, dim3(256, 15), dim3(256), 0, stream, spk_pool, Wpk, pot_out, mp);
  hipLaunchKernelGGL(k_inhib, dim3(256), dim3(64), 0, stream, pot_out, mp, win, nspv, valv, sv);
  hipLaunchKernelGGL(k_final, dim3(16, 15), dim3(256), 0, stream, win, sv, spk_out, pot_out);
  hipLaunchKernelGGL(k_select, dim3(1), dim3(256), 0, stream, win, nspv, valv, winners);
}

// Round 15
// 888.563 us; speedup vs baseline: 1.1299x; 1.1062x over previous
//
#include <hip/hip_runtime.h>
#include <cstdint>
#include <cstddef>

#define HW 16384  // 128*128
typedef float v2f __attribute__((ext_vector_type(2)));
typedef __attribute__((ext_vector_type(4))) float f32x4_t;
typedef __attribute__((ext_vector_type(8))) short bf16x8;

__device__ __forceinline__ unsigned short f2bf(float f) {
  unsigned int u = __float_as_uint(f);
  unsigned int r = (u + 0x7FFFu + ((u >> 16) & 1u)) >> 16;  // RNE
  return (unsigned short)r;
}

// ---------------- weight pack (round-12 exact) ----------------
// Region A (g < 9216): Wpk interleaved [mt(16)][kc(9)][lane(64)][hi8|mid8|lo8]
//   oc = mt*16 + (lane&15); k = kc*32 + (lane>>4)*8 + jj  (dense k = ic*9+tap, k<270)
//   w2 = hi + mid + lo EXACTLY (24-bit mantissa = 3 x 8-bit bf16 chunks).
// Region B: w1p pairs for conv1 (5 oc-groups of 6 -> 3 pairs).
__global__ __launch_bounds__(256) void k_packw(const float* __restrict__ w1,
                                               const float* __restrict__ w2,
                                               v2f* __restrict__ w1p,
                                               unsigned short* __restrict__ Wpk) {
  int g = blockIdx.x * 256 + threadIdx.x;
  if (g < 9216) {
    int mt = g / 576;
    int rem = g - mt * 576;
    int kc = rem >> 6, lane = rem & 63;
    int oc = mt * 16 + (lane & 15);
    unsigned int hbits[4], mbits[4], lbits[4];
#pragma unroll
    for (int p = 0; p < 4; ++p) { hbits[p] = 0; mbits[p] = 0; lbits[p] = 0; }
#pragma unroll
    for (int jj = 0; jj < 8; ++jj) {
      int k = kc * 32 + ((lane >> 4) << 3) + jj;
      float val = (oc < 250 && k < 270) ? w2[(size_t)oc * 270 + k] : 0.f;
      unsigned short h = f2bf(val);
      float r1 = val - __uint_as_float((unsigned int)h << 16);  // exact
      unsigned short m = f2bf(r1);
      float r2 = r1 - __uint_as_float((unsigned int)m << 16);   // exact
      unsigned short l = f2bf(r2);                              // exact: <=8 bits left
      hbits[jj >> 1] |= (unsigned int)h << ((jj & 1) * 16);
      mbits[jj >> 1] |= (unsigned int)m << ((jj & 1) * 16);
      lbits[jj >> 1] |= (unsigned int)l << ((jj & 1) * 16);
    }
    size_t off = (size_t)g * 24;
    *(uint4*)&Wpk[off] = make_uint4(hbits[0], hbits[1], hbits[2], hbits[3]);
    *(uint4*)&Wpk[off + 8] = make_uint4(mbits[0], mbits[1], mbits[2], mbits[3]);
    *(uint4*)&Wpk[off + 16] = make_uint4(lbits[0], lbits[1], lbits[2], lbits[3]);
    return;
  }
  int i = g - 9216;
  if (i < 2250) {
    int m = i % 3, k = (i / 3) % 25, ic = (i / 75) % 6, ocg = i / 450;
    int g0 = ocg * 6 + 2 * m;
    w1p[i] = (v2f){w1[(g0 * 6 + ic) * 25 + k], w1[((g0 + 1) * 6 + ic) * 25 + k]};
  }
}

// ---------------- conv1 + fire(15) + maxpool 2x2 (round-12 exact) ----------------
__global__ __launch_bounds__(256, 4) void k_conv1(const float* __restrict__ x,
                                                  const v2f* __restrict__ w1p,
                                                  uint8_t* __restrict__ spk_pool) {
  const int tile = blockIdx.x, ocg = blockIdx.y, t = blockIdx.z;
  const int oc0 = ocg * 6;
  const int tid = threadIdx.x;
  const int tx = tid & 15, ty = tid >> 4;
  const int px0 = (tile & 7) << 4, py0 = (tile >> 3) << 4;
  __shared__ float sx[2][36 * 38];
  const int iy0 = (py0 << 1) - 2, ix0 = (px0 << 1) - 2;  // pad=2

  int goff[6], soff[6];
  bool act[6];
#pragma unroll
  for (int j = 0; j < 6; ++j) {
    int idx = tid + 256 * j;
    bool a = idx < 1296;
    int r = idx / 36, c = idx - r * 36;
    int gy = iy0 + r, gx = ix0 + c;
    bool inb = a && (unsigned)gy < 256u && (unsigned)gx < 256u;
    goff[j] = inb ? ((gy << 8) + gx) : -1;
    soff[j] = a ? (r * 38 + c) : 0;
    act[j] = a;
  }

  v2f acc2[3][4];
#pragma unroll
  for (int m = 0; m < 3; ++m)
#pragma unroll
    for (int j = 0; j < 4; ++j) acc2[m][j] = (v2f){0.f, 0.f};

  const float* xt = x + ((size_t)(t * 6) << 16);
  float v[6];
#pragma unroll
  for (int j = 0; j < 6; ++j) v[j] = (goff[j] >= 0) ? xt[goff[j]] : 0.f;
#pragma unroll
  for (int j = 0; j < 6; ++j)
    if (act[j]) sx[0][soff[j]] = v[j];
  __syncthreads();

  for (int ic = 0; ic < 6; ++ic) {
    const int cur = ic & 1, nxt = cur ^ 1;
    if (ic < 5) {
      const float* xp = xt + ((size_t)(ic + 1) << 16);
#pragma unroll
      for (int j = 0; j < 6; ++j) v[j] = (goff[j] >= 0) ? xp[goff[j]] : 0.f;
    }
    float win_[6][6];
#pragma unroll
    for (int r = 0; r < 6; ++r) {
      float2 a = *(const float2*)&sx[cur][(2 * ty + r) * 38 + 2 * tx];
      float2 b = *(const float2*)&sx[cur][(2 * ty + r) * 38 + 2 * tx + 2];
      float2 c = *(const float2*)&sx[cur][(2 * ty + r) * 38 + 2 * tx + 4];
      win_[r][0] = a.x; win_[r][1] = a.y; win_[r][2] = b.x;
      win_[r][3] = b.y; win_[r][4] = c.x; win_[r][5] = c.y;
    }
    const v2f* wp = w1p + ((size_t)(ocg * 6 + ic) * 25) * 3;
#pragma unroll
    for (int k = 0; k < 25; ++k) {
      const int ky = k / 5, kx = k % 5;
      v2f s0 = (v2f){win_[ky][kx], win_[ky][kx]};
      v2f s1 = (v2f){win_[ky][kx + 1], win_[ky][kx + 1]};
      v2f s2 = (v2f){win_[ky + 1][kx], win_[ky + 1][kx]};
      v2f s3 = (v2f){win_[ky + 1][kx + 1], win_[ky + 1][kx + 1]};
#pragma unroll
      for (int m = 0; m < 3; ++m) {
        v2f wv = wp[k * 3 + m];  // block-uniform -> SGPR pair
        acc2[m][0] += wv * s0;
        acc2[m][1] += wv * s1;
        acc2[m][2] += wv * s2;
        acc2[m][3] += wv * s3;
      }
    }
    if (ic < 5) {
#pragma unroll
      for (int j = 0; j < 6; ++j)
        if (act[j]) sx[nxt][soff[j]] = v[j];
    }
    __syncthreads();
  }
#pragma unroll
  for (int g = 0; g < 6; ++g) {
    const int m = g >> 1;
    float a0 = (g & 1) ? acc2[m][0].y : acc2[m][0].x;
    float a1 = (g & 1) ? acc2[m][1].y : acc2[m][1].x;
    float a2 = (g & 1) ? acc2[m][2].y : acc2[m][2].x;
    float a3 = (g & 1) ? acc2[m][3].y : acc2[m][3].x;
    int spike = (a0 > 15.f) || (a1 > 15.f) || (a2 > 15.f) || (a3 > 15.f);
    spk_pool[((size_t)(t * 30 + oc0 + g) << 14) + ((size_t)(py0 + ty) << 7) + (px0 + tx)] =
        (uint8_t)spike;
  }
}

// ---------------- conv2 via MFMA (round-12 + block zero-skip) ----------------
// grid (256 n-tiles, 15 t), block 256 (4 waves). Block = 64 locs x all 250 ocs.
__global__ __launch_bounds__(256, 3) void k_conv2(const uint8_t* __restrict__ spk_pool,
                                                  const unsigned short* __restrict__ Wpk,
                                                  float* __restrict__ pot2,
                                                  unsigned long long* __restrict__ mp) {
  const int nt = blockIdx.x, t = blockIdx.y;
  const int y = nt >> 1, x0 = (nt & 1) << 6;
  const int tid = threadIdx.x;
  __shared__ unsigned short Bs[64 * 288];        // 36,864 B
  __shared__ unsigned char raw[30 * 3 * 68];     //  6,120 B
  __shared__ unsigned long long mx[64];
  __shared__ int sFlag[4];
  if (tid < 64) mx[tid] = 0ULL;

  // ---- stage raw stripe (coalesced byte loads) + zero detection ----
  unsigned int nz = 0;
  for (int idx = tid; idx < 30 * 204; idx += 256) {
    int ic = idx / 204;
    int rem = idx - ic * 204;
    int row = rem / 68, col = rem - row * 68;
    int gy = y - 1 + row, gx = x0 - 1 + col;
    unsigned char v = 0;
    if ((unsigned)gy < 128u && (unsigned)gx < 128u && col < 67)
      v = spk_pool[((size_t)(t * 30 + ic) << 14) + (gy << 7) + gx];
    raw[idx] = v;
    nz |= v;
  }
  {
    bool wnz = __any(nz != 0);
    if ((tid & 63) == 0) sFlag[tid >> 6] = wnz ? 1 : 0;
  }
  __syncthreads();
  const int flag = sFlag[0] | sFlag[1] | sFlag[2] | sFlag[3];

  const int w = tid >> 6, lane = tid & 63;
  const int bcol = lane & 15, bq = lane >> 4;
  f32x4_t acc[4][4];
#pragma unroll
  for (int i = 0; i < 4; ++i)
#pragma unroll
    for (int j = 0; j < 4; ++j) acc[i][j] = (f32x4_t){0.f, 0.f, 0.f, 0.f};

  if (flag) {
    // ---- expand to B panel: thread = (n = tid&63, q = tid>>6 covers k in [72q,72q+72)) ----
    const int n = tid & 63, q = tid >> 6;
#pragma unroll
    for (int c = 0; c < 9; ++c) {
      unsigned int bits[4] = {0u, 0u, 0u, 0u};
#pragma unroll
      for (int e = 0; e < 8; ++e) {
        const int m = c * 8 + e;        // 0..71, compile-time
        const int mc = m / 9, tap = m - mc * 9;
        const int dy = tap / 3, dx = tap - dy * 3;
        const int ic = q * 8 + mc;      // q runtime
        unsigned int v = 0u;
        if (ic < 30)
          v = raw[ic * 204 + dy * 68 + n + dx] ? 0x3F80u : 0u;
        bits[e >> 1] |= v << ((e & 1) * 16);
      }
      *(uint4*)&Bs[n * 288 + q * 72 + c * 8] = make_uint4(bits[0], bits[1], bits[2], bits[3]);
    }
    __syncthreads();

    // ---- MFMA main loop: 9 k-chunks of 32 ----
    for (int kc = 0; kc < 9; ++kc) {
      bf16x8 bb[4];
#pragma unroll
      for (int j = 0; j < 4; ++j)
        bb[j] = *(const bf16x8*)&Bs[(j * 16 + bcol) * 288 + kc * 32 + bq * 8];
      bf16x8 ah[4], am[4], al[4];
#pragma unroll
      for (int i = 0; i < 4; ++i) {
        const size_t off = (size_t)(((w * 4 + i) * 9 + kc) * 64 + lane) * 24;
        ah[i] = *(const bf16x8*)&Wpk[off];
        am[i] = *(const bf16x8*)&Wpk[off + 8];
        al[i] = *(const bf16x8*)&Wpk[off + 16];
      }
#pragma unroll
      for (int i = 0; i < 4; ++i)
#pragma unroll
        for (int j = 0; j < 4; ++j) {
          acc[i][j] = __builtin_amdgcn_mfma_f32_16x16x32_bf16(ah[i], bb[j], acc[i][j], 0, 0, 0);
          acc[i][j] = __builtin_amdgcn_mfma_f32_16x16x32_bf16(am[i], bb[j], acc[i][j], 0, 0, 0);
          acc[i][j] = __builtin_amdgcn_mfma_f32_16x16x32_bf16(al[i], bb[j], acc[i][j], 0, 0, 0);
        }
    }
  }

  // ---- epilogue: fire(10) + pot2 store + per-loc packed max ----
  // C/D layout: col(n) = lane&15, row(m) = (lane>>4)*4 + reg
#pragma unroll
  for (int j = 0; j < 4; ++j) {
    const int loc = (y << 7) + x0 + j * 16 + bcol;
    unsigned long long best = 0ULL;
#pragma unroll
    for (int i = 0; i < 4; ++i) {
      const int mt = w * 4 + i;
#pragma unroll
      for (int r = 0; r < 4; ++r) {
        const int oc = mt * 16 + (bq << 2) + r;
        float v = acc[i][j][r];
        v = v > 10.f ? v : 0.f;
        if (oc < 250) {
          pot2[((size_t)(t * 250 + oc) << 14) + loc] = v;
          unsigned long long pk =
              ((unsigned long long)__float_as_uint(v) << 32) |
              (unsigned long long)(1023 - oc);
          best = pk > best ? pk : best;
        }
      }
    }
    atomicMax(&mx[j * 16 + bcol], best);
  }
  __syncthreads();
  if (tid < 64) mp[(size_t)t * HW + (y << 7) + x0 + tid] = mx[tid];
}

// ---------------- inhibition combine per location (round-12 exact) ----------------
__global__ __launch_bounds__(64) void k_inhib(const float* __restrict__ pot2,
                                              const unsigned long long* __restrict__ mp,
                                              int* __restrict__ win,
                                              float* __restrict__ nspv,
                                              float* __restrict__ valv,
                                              float* __restrict__ sv) {
  const int loc = (blockIdx.x << 6) + threadIdx.x;
  int cnt = 0;
  float last = 0.f;
  unsigned long long pks[15];
#pragma unroll
  for (int t = 0; t < 15; ++t) {
    pks[t] = mp[t * HW + loc];
    float v = __uint_as_float((unsigned)(pks[t] >> 32));
    cnt += (v > 0.f) ? 1 : 0;
    if (t == 14) last = v;
  }
  const int spiked = (last > 0.f) ? 1 : 0;
  int ft = 15 - cnt;
  if (ft > 14) ft = 14;
  if (ft < 0) ft = 0;
  int wc = 1023 - (int)(pks[ft] & 1023ULL);
  if ((unsigned)wc > 249u) wc = 0;
  int nsp = 0;
#pragma unroll
  for (int t = 0; t < 15; ++t) {
    float v = pot2[((size_t)(t * 250 + wc) << 14) + loc];
    v = spiked ? v : 0.f;
    sv[t * HW + loc] = v;
    nsp += (v > 0.f) ? 1 : 0;
  }
  int ft2 = 15 - nsp;
  if (ft2 > 14) ft2 = 14;
  float value = spiked ? pot2[((size_t)(ft2 * 250 + wc) << 14) + loc] : 0.f;
  win[loc] = spiked ? wc : -1;
  nspv[loc] = (float)nsp;
  valv[loc] = value;
}

// ---------------- finalize: loc-major scalar (round-12 exact: 960 blocks) ----------------
// grid (64, 15), block 256. Thread = 1 loc, loops 250 channels.
__global__ __launch_bounds__(256) void k_final(const int* __restrict__ win,
                                               const float* __restrict__ sv,
                                               float* __restrict__ spk_out,
                                               float* __restrict__ pot_out) {
  const int t = blockIdx.y;
  const int loc = (blockIdx.x << 8) + threadIdx.x;
  const int wcL = win[loc];
  const float v = sv[t * HW + loc];
  const float s = (v > 0.f) ? 1.f : 0.f;
  float* pp = pot_out + ((size_t)(t * 250) << 14) + loc;
  float* sp = spk_out + ((size_t)(t * 250) << 14) + loc;
  for (int c = 0; c < 250; ++c) {
    pp[(size_t)c << 14] = (c == wcL) ? v : 0.f;
    sp[(size_t)c << 14] = (c == wcL) ? s : 0.f;
  }
}

// ---------------- k-winner selection (single block, round-12 exact) ----------------
__global__ __launch_bounds__(256) void k_select(const int* __restrict__ win,
                                                const float* __restrict__ nspv,
                                                const float* __restrict__ valv,
                                                float* __restrict__ winners) {
  __shared__ float tot[HW];
  __shared__ int wchan[HW];
  __shared__ float redV[256];
  __shared__ int redK[256];
  __shared__ float bcValid[1];
  __shared__ int bcKey[1];
  const int tid = threadIdx.x;

  float lmax = 0.f;
  for (int i = tid; i < HW; i += 256) {
    wchan[i] = win[i];
    lmax = fmaxf(lmax, valv[i]);
  }
  redV[tid] = lmax;
  __syncthreads();
  for (int s = 128; s > 0; s >>= 1) {
    if (tid < s) redV[tid] = fmaxf(redV[tid], redV[tid + s]);
    __syncthreads();
  }
  const float v15 = redV[0] * 15.f;
  __syncthreads();
  for (int i = tid; i < HW; i += 256) tot[i] = nspv[i] * (valv[i] + v15);
  __syncthreads();

  for (int k = 0; k < 8; ++k) {
    float bv = -1.f;
    int bkey = 0x7fffffff;
    for (int i = tid; i < HW; i += 256) {
      float v = tot[i];
      int key = (wchan[i] << 14) + i;
      if (v > bv || (v == bv && key < bkey)) { bv = v; bkey = key; }
    }
    redV[tid] = bv;
    redK[tid] = bkey;
    __syncthreads();
    for (int s = 128; s > 0; s >>= 1) {
      if (tid < s) {
        float ov = redV[tid + s];
        int ok = redK[tid + s];
        if (ov > redV[tid] || (ov == redV[tid] && ok < redK[tid])) {
          redV[tid] = ov;
          redK[tid] = ok;
        }
      }
      __syncthreads();
    }
    if (tid == 0) {
      float mv = redV[0];
      int mk = redK[0];
      int valid = (mv != 0.f) ? 1 : 0;
      int c = mk >> 14, l = mk & (HW - 1);
      winners[k * 3 + 0] = valid ? (float)c : -1.f;
      winners[k * 3 + 1] = valid ? (float)(l >> 7) : -1.f;
      winners[k * 3 + 2] = valid ? (float)(l & 127) : -1.f;
      bcValid[0] = valid ? 1.f : 0.f;
      bcKey[0] = mk;
    }
    __syncthreads();
    if (bcValid[0] > 0.f) {
      int mk = bcKey[0];
      int c = mk >> 14, h = (mk & (HW - 1)) >> 7, w = mk & 127;
      for (int i = tid; i < HW; i += 256) {
        int hh = i >> 7, ww = i & 127;
        int dh = hh - h; if (dh < 0) dh = -dh;
        int dw = ww - w; if (dw < 0) dw = -dw;
        bool m = (wchan[i] == c) || (dh <= 1 && dw <= 1);
        if (m) tot[i] = 0.f;
      }
    }
    __syncthreads();
  }
}

extern "C" void kernel_launch(void* const* d_in, const int* in_sizes, int n_in,
                              void* d_out, int out_size, void* d_ws, size_t ws_size,
                              hipStream_t stream) {
  const float* x = (const float*)d_in[0];
  const float* w1 = (const float*)d_in[1];
  const float* w2 = (const float*)d_in[2];
  (void)in_sizes; (void)n_in; (void)out_size; (void)ws_size;

  float* spk_out = (float*)d_out;
  float* pot_out = spk_out + 61440000;  // pot2 scratch == final pot at winner ch
  float* winners = spk_out + 122880000;

  uint8_t* ws = (uint8_t*)d_ws;
  unsigned long long* mp = (unsigned long long*)ws;   // 1,966,080 B u64 [15][HW]
  uint8_t* spk_pool = ws + 1966080;                   // 7,372,800 B u8
  int* win = (int*)(ws + 9338880);                    //  65,536 B
  float* nspv = (float*)(ws + 9404416);               //  65,536 B
  float* valv = (float*)(ws + 9469952);               //  65,536 B
  float* sv = (float*)(ws + 9535488);                 // 983,040 B [15][HW]
  // Wpk overlaps sv: dead until k_inhib writes sv (conv2 finished reading)
  unsigned short* Wpk = (unsigned short*)(ws + 9535488);  // 442,368 B
  v2f* w1p = (v2f*)(ws + 10518528);                   //  18,000 B

  hipLaunchKernelGGL(k_packw, dim3(45), dim3(256), 0, stream, w1, w2, w1p, Wpk);
  hipLaunchKernelGGL(k_conv1, dim3(64, 5, 15), dim3(256), 0, stream, x, w1p, spk_pool);
  hipLaunchKernelGGL(k_conv2, dim3(256, 15), dim3(256), 0, stream, spk_pool, Wpk, pot_out, mp);
  hipLaunchKernelGGL(k_inhib, dim3(256), dim3(64), 0, stream, pot_out, mp, win, nspv, valv, sv);
  hipLaunchKernelGGL(k_final, dim3(64, 15), dim3(256), 0, stream, win, sv, spk_out, pot_out);
  hipLaunchKernelGGL(k_select, dim3(1), dim3(256), 0, stream, win, nspv, valv, winners);
}

// Round 16
// 855.182 us; speedup vs baseline: 1.1740x; 1.0390x over previous
//
#include <hip/hip_runtime.h>
#include <cstdint>
#include <cstddef>

#define HW 16384  // 128*128
typedef float v2f __attribute__((ext_vector_type(2)));
typedef __attribute__((ext_vector_type(4))) float f32x4_t;
typedef __attribute__((ext_vector_type(8))) short bf16x8;

__device__ __forceinline__ unsigned short f2bf(float f) {
  unsigned int u = __float_as_uint(f);
  unsigned int r = (u + 0x7FFFu + ((u >> 16) & 1u)) >> 16;  // RNE
  return (unsigned short)r;
}

// ---------------- weight pack (round-12 exact) ----------------
__global__ __launch_bounds__(256) void k_packw(const float* __restrict__ w1,
                                               const float* __restrict__ w2,
                                               v2f* __restrict__ w1p,
                                               unsigned short* __restrict__ Wpk) {
  int g = blockIdx.x * 256 + threadIdx.x;
  if (g < 9216) {
    int mt = g / 576;
    int rem = g - mt * 576;
    int kc = rem >> 6, lane = rem & 63;
    int oc = mt * 16 + (lane & 15);
    unsigned int hbits[4], mbits[4], lbits[4];
#pragma unroll
    for (int p = 0; p < 4; ++p) { hbits[p] = 0; mbits[p] = 0; lbits[p] = 0; }
#pragma unroll
    for (int jj = 0; jj < 8; ++jj) {
      int k = kc * 32 + ((lane >> 4) << 3) + jj;
      float val = (oc < 250 && k < 270) ? w2[(size_t)oc * 270 + k] : 0.f;
      unsigned short h = f2bf(val);
      float r1 = val - __uint_as_float((unsigned int)h << 16);  // exact
      unsigned short m = f2bf(r1);
      float r2 = r1 - __uint_as_float((unsigned int)m << 16);   // exact
      unsigned short l = f2bf(r2);                              // exact: <=8 bits left
      hbits[jj >> 1] |= (unsigned int)h << ((jj & 1) * 16);
      mbits[jj >> 1] |= (unsigned int)m << ((jj & 1) * 16);
      lbits[jj >> 1] |= (unsigned int)l << ((jj & 1) * 16);
    }
    size_t off = (size_t)g * 24;
    *(uint4*)&Wpk[off] = make_uint4(hbits[0], hbits[1], hbits[2], hbits[3]);
    *(uint4*)&Wpk[off + 8] = make_uint4(mbits[0], mbits[1], mbits[2], mbits[3]);
    *(uint4*)&Wpk[off + 16] = make_uint4(lbits[0], lbits[1], lbits[2], lbits[3]);
    return;
  }
  int i = g - 9216;
  if (i < 2250) {
    int m = i % 3, k = (i / 3) % 25, ic = (i / 75) % 6, ocg = i / 450;
    int g0 = ocg * 6 + 2 * m;
    w1p[i] = (v2f){w1[(g0 * 6 + ic) * 25 + k], w1[((g0 + 1) * 6 + ic) * 25 + k]};
  }
}

// ---------------- conv1 + fire(15) + maxpool 2x2 (round-12 exact) ----------------
__global__ __launch_bounds__(256, 4) void k_conv1(const float* __restrict__ x,
                                                  const v2f* __restrict__ w1p,
                                                  uint8_t* __restrict__ spk_pool) {
  const int tile = blockIdx.x, ocg = blockIdx.y, t = blockIdx.z;
  const int oc0 = ocg * 6;
  const int tid = threadIdx.x;
  const int tx = tid & 15, ty = tid >> 4;
  const int px0 = (tile & 7) << 4, py0 = (tile >> 3) << 4;
  __shared__ float sx[2][36 * 38];
  const int iy0 = (py0 << 1) - 2, ix0 = (px0 << 1) - 2;  // pad=2

  int goff[6], soff[6];
  bool act[6];
#pragma unroll
  for (int j = 0; j < 6; ++j) {
    int idx = tid + 256 * j;
    bool a = idx < 1296;
    int r = idx / 36, c = idx - r * 36;
    int gy = iy0 + r, gx = ix0 + c;
    bool inb = a && (unsigned)gy < 256u && (unsigned)gx < 256u;
    goff[j] = inb ? ((gy << 8) + gx) : -1;
    soff[j] = a ? (r * 38 + c) : 0;
    act[j] = a;
  }

  v2f acc2[3][4];
#pragma unroll
  for (int m = 0; m < 3; ++m)
#pragma unroll
    for (int j = 0; j < 4; ++j) acc2[m][j] = (v2f){0.f, 0.f};

  const float* xt = x + ((size_t)(t * 6) << 16);
  float v[6];
#pragma unroll
  for (int j = 0; j < 6; ++j) v[j] = (goff[j] >= 0) ? xt[goff[j]] : 0.f;
#pragma unroll
  for (int j = 0; j < 6; ++j)
    if (act[j]) sx[0][soff[j]] = v[j];
  __syncthreads();

  for (int ic = 0; ic < 6; ++ic) {
    const int cur = ic & 1, nxt = cur ^ 1;
    if (ic < 5) {
      const float* xp = xt + ((size_t)(ic + 1) << 16);
#pragma unroll
      for (int j = 0; j < 6; ++j) v[j] = (goff[j] >= 0) ? xp[goff[j]] : 0.f;
    }
    float win_[6][6];
#pragma unroll
    for (int r = 0; r < 6; ++r) {
      float2 a = *(const float2*)&sx[cur][(2 * ty + r) * 38 + 2 * tx];
      float2 b = *(const float2*)&sx[cur][(2 * ty + r) * 38 + 2 * tx + 2];
      float2 c = *(const float2*)&sx[cur][(2 * ty + r) * 38 + 2 * tx + 4];
      win_[r][0] = a.x; win_[r][1] = a.y; win_[r][2] = b.x;
      win_[r][3] = b.y; win_[r][4] = c.x; win_[r][5] = c.y;
    }
    const v2f* wp = w1p + ((size_t)(ocg * 6 + ic) * 25) * 3;
#pragma unroll
    for (int k = 0; k < 25; ++k) {
      const int ky = k / 5, kx = k % 5;
      v2f s0 = (v2f){win_[ky][kx], win_[ky][kx]};
      v2f s1 = (v2f){win_[ky][kx + 1], win_[ky][kx + 1]};
      v2f s2 = (v2f){win_[ky + 1][kx], win_[ky + 1][kx]};
      v2f s3 = (v2f){win_[ky + 1][kx + 1], win_[ky + 1][kx + 1]};
#pragma unroll
      for (int m = 0; m < 3; ++m) {
        v2f wv = wp[k * 3 + m];  // block-uniform -> SGPR pair
        acc2[m][0] += wv * s0;
        acc2[m][1] += wv * s1;
        acc2[m][2] += wv * s2;
        acc2[m][3] += wv * s3;
      }
    }
    if (ic < 5) {
#pragma unroll
      for (int j = 0; j < 6; ++j)
        if (act[j]) sx[nxt][soff[j]] = v[j];
    }
    __syncthreads();
  }
#pragma unroll
  for (int g = 0; g < 6; ++g) {
    const int m = g >> 1;
    float a0 = (g & 1) ? acc2[m][0].y : acc2[m][0].x;
    float a1 = (g & 1) ? acc2[m][1].y : acc2[m][1].x;
    float a2 = (g & 1) ? acc2[m][2].y : acc2[m][2].x;
    float a3 = (g & 1) ? acc2[m][3].y : acc2[m][3].x;
    int spike = (a0 > 15.f) || (a1 > 15.f) || (a2 > 15.f) || (a3 > 15.f);
    spk_pool[((size_t)(t * 30 + oc0 + g) << 14) + ((size_t)(py0 + ty) << 7) + (px0 + tx)] =
        (uint8_t)spike;
  }
}

// ---------------- conv2 via MFMA (round-15 exact: dense K=288 + zero-skip) ----------------
__global__ __launch_bounds__(256, 3) void k_conv2(const uint8_t* __restrict__ spk_pool,
                                                  const unsigned short* __restrict__ Wpk,
                                                  float* __restrict__ pot2,
                                                  unsigned long long* __restrict__ mp) {
  const int nt = blockIdx.x, t = blockIdx.y;
  const int y = nt >> 1, x0 = (nt & 1) << 6;
  const int tid = threadIdx.x;
  __shared__ unsigned short Bs[64 * 288];        // 36,864 B
  __shared__ unsigned char raw[30 * 3 * 68];     //  6,120 B
  __shared__ unsigned long long mx[64];
  __shared__ int sFlag[4];
  if (tid < 64) mx[tid] = 0ULL;

  // ---- stage raw stripe (coalesced byte loads) + zero detection ----
  unsigned int nz = 0;
  for (int idx = tid; idx < 30 * 204; idx += 256) {
    int ic = idx / 204;
    int rem = idx - ic * 204;
    int row = rem / 68, col = rem - row * 68;
    int gy = y - 1 + row, gx = x0 - 1 + col;
    unsigned char v = 0;
    if ((unsigned)gy < 128u && (unsigned)gx < 128u && col < 67)
      v = spk_pool[((size_t)(t * 30 + ic) << 14) + (gy << 7) + gx];
    raw[idx] = v;
    nz |= v;
  }
  {
    bool wnz = __any(nz != 0);
    if ((tid & 63) == 0) sFlag[tid >> 6] = wnz ? 1 : 0;
  }
  __syncthreads();
  const int flag = sFlag[0] | sFlag[1] | sFlag[2] | sFlag[3];

  const int w = tid >> 6, lane = tid & 63;
  const int bcol = lane & 15, bq = lane >> 4;
  f32x4_t acc[4][4];
#pragma unroll
  for (int i = 0; i < 4; ++i)
#pragma unroll
    for (int j = 0; j < 4; ++j) acc[i][j] = (f32x4_t){0.f, 0.f, 0.f, 0.f};

  if (flag) {
    // ---- expand to B panel ----
    const int n = tid & 63, q = tid >> 6;
#pragma unroll
    for (int c = 0; c < 9; ++c) {
      unsigned int bits[4] = {0u, 0u, 0u, 0u};
#pragma unroll
      for (int e = 0; e < 8; ++e) {
        const int m = c * 8 + e;        // 0..71, compile-time
        const int mc = m / 9, tap = m - mc * 9;
        const int dy = tap / 3, dx = tap - dy * 3;
        const int ic = q * 8 + mc;      // q runtime
        unsigned int v = 0u;
        if (ic < 30)
          v = raw[ic * 204 + dy * 68 + n + dx] ? 0x3F80u : 0u;
        bits[e >> 1] |= v << ((e & 1) * 16);
      }
      *(uint4*)&Bs[n * 288 + q * 72 + c * 8] = make_uint4(bits[0], bits[1], bits[2], bits[3]);
    }
    __syncthreads();

    // ---- MFMA main loop: 9 k-chunks of 32 ----
    for (int kc = 0; kc < 9; ++kc) {
      bf16x8 bb[4];
#pragma unroll
      for (int j = 0; j < 4; ++j)
        bb[j] = *(const bf16x8*)&Bs[(j * 16 + bcol) * 288 + kc * 32 + bq * 8];
      bf16x8 ah[4], am[4], al[4];
#pragma unroll
      for (int i = 0; i < 4; ++i) {
        const size_t off = (size_t)(((w * 4 + i) * 9 + kc) * 64 + lane) * 24;
        ah[i] = *(const bf16x8*)&Wpk[off];
        am[i] = *(const bf16x8*)&Wpk[off + 8];
        al[i] = *(const bf16x8*)&Wpk[off + 16];
      }
#pragma unroll
      for (int i = 0; i < 4; ++i)
#pragma unroll
        for (int j = 0; j < 4; ++j) {
          acc[i][j] = __builtin_amdgcn_mfma_f32_16x16x32_bf16(ah[i], bb[j], acc[i][j], 0, 0, 0);
          acc[i][j] = __builtin_amdgcn_mfma_f32_16x16x32_bf16(am[i], bb[j], acc[i][j], 0, 0, 0);
          acc[i][j] = __builtin_amdgcn_mfma_f32_16x16x32_bf16(al[i], bb[j], acc[i][j], 0, 0, 0);
        }
    }
  }

  // ---- epilogue: fire(10) + pot2 store + per-loc packed max ----
  // C/D layout: col(n) = lane&15, row(m) = (lane>>4)*4 + reg
#pragma unroll
  for (int j = 0; j < 4; ++j) {
    const int loc = (y << 7) + x0 + j * 16 + bcol;
    unsigned long long best = 0ULL;
#pragma unroll
    for (int i = 0; i < 4; ++i) {
      const int mt = w * 4 + i;
#pragma unroll
      for (int r = 0; r < 4; ++r) {
        const int oc = mt * 16 + (bq << 2) + r;
        float v = acc[i][j][r];
        v = v > 10.f ? v : 0.f;
        if (oc < 250) {
          pot2[((size_t)(t * 250 + oc) << 14) + loc] = v;
          unsigned long long pk =
              ((unsigned long long)__float_as_uint(v) << 32) |
              (unsigned long long)(1023 - oc);
          best = pk > best ? pk : best;
        }
      }
    }
    atomicMax(&mx[j * 16 + bcol], best);
  }
  __syncthreads();
  if (tid < 64) mp[(size_t)t * HW + (y << 7) + x0 + tid] = mx[tid];
}

// ---------------- inhibition combine per location (round-12 exact) ----------------
__global__ __launch_bounds__(64) void k_inhib(const float* __restrict__ pot2,
                                              const unsigned long long* __restrict__ mp,
                                              int* __restrict__ win,
                                              float* __restrict__ nspv,
                                              float* __restrict__ valv,
                                              float* __restrict__ sv) {
  const int loc = (blockIdx.x << 6) + threadIdx.x;
  int cnt = 0;
  float last = 0.f;
  unsigned long long pks[15];
#pragma unroll
  for (int t = 0; t < 15; ++t) {
    pks[t] = mp[t * HW + loc];
    float v = __uint_as_float((unsigned)(pks[t] >> 32));
    cnt += (v > 0.f) ? 1 : 0;
    if (t == 14) last = v;
  }
  const int spiked = (last > 0.f) ? 1 : 0;
  int ft = 15 - cnt;
  if (ft > 14) ft = 14;
  if (ft < 0) ft = 0;
  int wc = 1023 - (int)(pks[ft] & 1023ULL);
  if ((unsigned)wc > 249u) wc = 0;
  int nsp = 0;
#pragma unroll
  for (int t = 0; t < 15; ++t) {
    float v = pot2[((size_t)(t * 250 + wc) << 14) + loc];
    v = spiked ? v : 0.f;
    sv[t * HW + loc] = v;
    nsp += (v > 0.f) ? 1 : 0;
  }
  int ft2 = 15 - nsp;
  if (ft2 > 14) ft2 = 14;
  float value = spiked ? pot2[((size_t)(ft2 * 250 + wc) << 14) + loc] : 0.f;
  win[loc] = spiked ? wc : -1;
  nspv[loc] = (float)nsp;
  valv[loc] = value;
}

// ---------------- finalize: channel-partitioned, nontemporal stores ----------------
// grid (320, 15) = 64 loc-blocks x 5 channel-groups of 50. Thread = 1 loc, 50 channels.
__global__ __launch_bounds__(256) void k_final(const int* __restrict__ win,
                                               const float* __restrict__ sv,
                                               float* __restrict__ spk_out,
                                               float* __restrict__ pot_out) {
  const int t = blockIdx.y;
  const int lb = blockIdx.x & 63, cg = blockIdx.x >> 6;
  const int loc = (lb << 8) + threadIdx.x;
  const int wcL = win[loc];
  const float v = sv[t * HW + loc];
  const float s = (v > 0.f) ? 1.f : 0.f;
  const int c0 = cg * 50;
  float* pp = pot_out + ((size_t)(t * 250 + c0) << 14) + loc;
  float* sp = spk_out + ((size_t)(t * 250 + c0) << 14) + loc;
#pragma unroll 5
  for (int c = c0; c < c0 + 50; ++c) {
    __builtin_nontemporal_store((c == wcL) ? v : 0.f, pp);
    __builtin_nontemporal_store((c == wcL) ? s : 0.f, sp);
    pp += HW;
    sp += HW;
  }
}

// ---------------- k-winner selection (single block, round-12 exact) ----------------
__global__ __launch_bounds__(256) void k_select(const int* __restrict__ win,
                                                const float* __restrict__ nspv,
                                                const float* __restrict__ valv,
                                                float* __restrict__ winners) {
  __shared__ float tot[HW];
  __shared__ int wchan[HW];
  __shared__ float redV[256];
  __shared__ int redK[256];
  __shared__ float bcValid[1];
  __shared__ int bcKey[1];
  const int tid = threadIdx.x;

  float lmax = 0.f;
  for (int i = tid; i < HW; i += 256) {
    wchan[i] = win[i];
    lmax = fmaxf(lmax, valv[i]);
  }
  redV[tid] = lmax;
  __syncthreads();
  for (int s = 128; s > 0; s >>= 1) {
    if (tid < s) redV[tid] = fmaxf(redV[tid], redV[tid + s]);
    __syncthreads();
  }
  const float v15 = redV[0] * 15.f;
  __syncthreads();
  for (int i = tid; i < HW; i += 256) tot[i] = nspv[i] * (valv[i] + v15);
  __syncthreads();

  for (int k = 0; k < 8; ++k) {
    float bv = -1.f;
    int bkey = 0x7fffffff;
    for (int i = tid; i < HW; i += 256) {
      float v = tot[i];
      int key = (wchan[i] << 14) + i;
      if (v > bv || (v == bv && key < bkey)) { bv = v; bkey = key; }
    }
    redV[tid] = bv;
    redK[tid] = bkey;
    __syncthreads();
    for (int s = 128; s > 0; s >>= 1) {
      if (tid < s) {
        float ov = redV[tid + s];
        int ok = redK[tid + s];
        if (ov > redV[tid] || (ov == redV[tid] && ok < redK[tid])) {
          redV[tid] = ov;
          redK[tid] = ok;
        }
      }
      __syncthreads();
    }
    if (tid == 0) {
      float mv = redV[0];
      int mk = redK[0];
      int valid = (mv != 0.f) ? 1 : 0;
      int c = mk >> 14, l = mk & (HW - 1);
      winners[k * 3 + 0] = valid ? (float)c : -1.f;
      winners[k * 3 + 1] = valid ? (float)(l >> 7) : -1.f;
      winners[k * 3 + 2] = valid ? (float)(l & 127) : -1.f;
      bcValid[0] = valid ? 1.f : 0.f;
      bcKey[0] = mk;
    }
    __syncthreads();
    if (bcValid[0] > 0.f) {
      int mk = bcKey[0];
      int c = mk >> 14, h = (mk & (HW - 1)) >> 7, w = mk & 127;
      for (int i = tid; i < HW; i += 256) {
        int hh = i >> 7, ww = i & 127;
        int dh = hh - h; if (dh < 0) dh = -dh;
        int dw = ww - w; if (dw < 0) dw = -dw;
        bool m = (wchan[i] == c) || (dh <= 1 && dw <= 1);
        if (m) tot[i] = 0.f;
      }
    }
    __syncthreads();
  }
}

extern "C" void kernel_launch(void* const* d_in, const int* in_sizes, int n_in,
                              void* d_out, int out_size, void* d_ws, size_t ws_size,
                              hipStream_t stream) {
  const float* x = (const float*)d_in[0];
  const float* w1 = (const float*)d_in[1];
  const float* w2 = (const float*)d_in[2];
  (void)in_sizes; (void)n_in; (void)out_size; (void)ws_size;

  float* spk_out = (float*)d_out;
  float* pot_out = spk_out + 61440000;  // pot2 scratch == final pot at winner ch
  float* winners = spk_out + 122880000;

  uint8_t* ws = (uint8_t*)d_ws;
  unsigned long long* mp = (unsigned long long*)ws;   // 1,966,080 B u64 [15][HW]
  uint8_t* spk_pool = ws + 1966080;                   // 7,372,800 B u8
  int* win = (int*)(ws + 9338880);                    //  65,536 B
  float* nspv = (float*)(ws + 9404416);               //  65,536 B
  float* valv = (float*)(ws + 9469952);               //  65,536 B
  float* sv = (float*)(ws + 9535488);                 // 983,040 B [15][HW]
  // Wpk overlaps sv: dead until k_inhib writes sv (conv2 finished reading)
  unsigned short* Wpk = (unsigned short*)(ws + 9535488);  // 442,368 B
  v2f* w1p = (v2f*)(ws + 10518528);                   //  18,000 B

  hipLaunchKernelGGL(k_packw, dim3(45), dim3(256), 0, stream, w1, w2, w1p, Wpk);
  hipLaunchKernelGGL(k_conv1, dim3(64, 5, 15), dim3(256), 0, stream, x, w1p, spk_pool);
  hipLaunchKernelGGL(k_conv2, dim3(256, 15), dim3(256), 0, stream, spk_pool, Wpk, pot_out, mp);
  hipLaunchKernelGGL(k_inhib, dim3(256), dim3(64), 0, stream, pot_out, mp, win, nspv, valv, sv);
  hipLaunchKernelGGL(k_final, dim3(320, 15), dim3(256), 0, stream, win, sv, spk_out, pot_out);
  hipLaunchKernelGGL(k_select, dim3(1), dim3(256), 0, stream, win, nspv, valv, winners);
}